// Round 1
// baseline (476.911 us; speedup 1.0000x reference)
//
#include <hip/hip_runtime.h>

#define BN 512            // matrix dimension n
#define NW 16             // waves per block (1024 threads)
#define RPW (BN / NW)     // rows per wave = 32

// Z = logits / TAU; work in base-2: Yl = Z * log2(e) = logits * (20 * 1.4426950408889634)
static constexpr float kScale = 28.853900817779268f;

__device__ __forceinline__ float fexp2(float x) { return __builtin_amdgcn_exp2f(x); }
__device__ __forceinline__ float flog2(float x) { return __builtin_amdgcn_logf(x); }

__global__ __launch_bounds__(1024, 1) void sinkhorn_fused(
    const float* __restrict__ logits, float* __restrict__ out)
{
    __shared__ float U[BN];          // row potentials (log2 domain)
    __shared__ float V[BN];          // col potentials (log2 domain)
    __shared__ float cred[NW][BN];   // per-wave column partial sums (32 KB)

    const int b = blockIdx.x;
    const size_t base = (size_t)b * BN * BN;
    const float* __restrict__ Zb = logits + base;
    float* __restrict__ Ob = out + base;

    const int tid  = threadIdx.x;
    const int lane = tid & 63;
    const int wave = tid >> 6;
    // each lane owns 8 columns: [4*lane .. 4*lane+3] and [256+4*lane .. 256+4*lane+3]
    const int c0 = lane * 4;
    const int c1 = lane * 4 + 256;

    if (tid < BN) { U[tid] = 0.0f; V[tid] = 0.0f; }
    __syncthreads();

    for (int it = 0; it < 10; ++it) {
        // V_prev into registers (fixed for the whole pass)
        float v0[4], v1[4];
        #pragma unroll
        for (int k = 0; k < 4; ++k) { v0[k] = V[c0 + k]; v1[k] = V[c1 + k]; }

        float ca0[4] = {0.f, 0.f, 0.f, 0.f};
        float ca1[4] = {0.f, 0.f, 0.f, 0.f};

        for (int r = 0; r < RPW; ++r) {
            const int i = wave * RPW + r;
            const float4 x0 = *reinterpret_cast<const float4*>(Zb + (size_t)i * BN + c0);
            const float4 x1 = *reinterpret_cast<const float4*>(Zb + (size_t)i * BN + c1);

            float t[8];
            t[0] = fmaf(x0.x, kScale, v0[0]);
            t[1] = fmaf(x0.y, kScale, v0[1]);
            t[2] = fmaf(x0.z, kScale, v0[2]);
            t[3] = fmaf(x0.w, kScale, v0[3]);
            t[4] = fmaf(x1.x, kScale, v1[0]);
            t[5] = fmaf(x1.y, kScale, v1[1]);
            t[6] = fmaf(x1.z, kScale, v1[2]);
            t[7] = fmaf(x1.w, kScale, v1[3]);

            float off;
            if (it == 0) {
                // raw LSE of Z/tau can overflow 2^127 -> exact max-subtraction,
                // the whole row lives in the wave's registers.
                float m = t[0];
                #pragma unroll
                for (int k = 1; k < 8; ++k) m = fmaxf(m, t[k]);
                #pragma unroll
                for (int d = 32; d > 0; d >>= 1) m = fmaxf(m, __shfl_xor(m, d, 64));
                off = -m;
            } else {
                // offset by U_prev: terms are entries of a row-normalized matrix -> <= 1,
                // sums provably in [2^-9, 2^9]; no max tracking needed.
                off = U[i];   // wave-uniform broadcast
            }

            float p[8];
            float s = 0.f;
            #pragma unroll
            for (int k = 0; k < 8; ++k) { p[k] = fexp2(t[k] + off); s += p[k]; }
            #pragma unroll
            for (int d = 32; d > 0; d >>= 1) s += __shfl_xor(s, d, 64);

            const float Unew = off - flog2(s);
            const float w = __builtin_amdgcn_rcpf(s);   // = 2^(Unew - off)
            if (lane == 0) U[i] = Unew;

            // fused col-pass contribution: 2^(Yl + U_new + V_prev) = p * (1/s)
            #pragma unroll
            for (int k = 0; k < 4; ++k) ca0[k] = fmaf(p[k],     w, ca0[k]);
            #pragma unroll
            for (int k = 0; k < 4; ++k) ca1[k] = fmaf(p[4 + k], w, ca1[k]);
        }

        // reduce column partials across waves, update V
        #pragma unroll
        for (int k = 0; k < 4; ++k) { cred[wave][c0 + k] = ca0[k]; cred[wave][c1 + k] = ca1[k]; }
        __syncthreads();

        if (tid < BN) {
            float s = 0.f;
            #pragma unroll
            for (int wv = 0; wv < NW; ++wv) s += cred[wv][tid];
            V[tid] = V[tid] - flog2(s);   // == -log2 sum_i 2^(Yl + U_new_i)
        }
        __syncthreads();
    }

    // output pass: out = 2^(Yl + U_i + V_j)
    {
        float v0[4], v1[4];
        #pragma unroll
        for (int k = 0; k < 4; ++k) { v0[k] = V[c0 + k]; v1[k] = V[c1 + k]; }

        for (int r = 0; r < RPW; ++r) {
            const int i = wave * RPW + r;
            const float Ui = U[i];
            const float4 x0 = *reinterpret_cast<const float4*>(Zb + (size_t)i * BN + c0);
            const float4 x1 = *reinterpret_cast<const float4*>(Zb + (size_t)i * BN + c1);
            float4 o0, o1;
            o0.x = fexp2(fmaf(x0.x, kScale, v0[0]) + Ui);
            o0.y = fexp2(fmaf(x0.y, kScale, v0[1]) + Ui);
            o0.z = fexp2(fmaf(x0.z, kScale, v0[2]) + Ui);
            o0.w = fexp2(fmaf(x0.w, kScale, v0[3]) + Ui);
            o1.x = fexp2(fmaf(x1.x, kScale, v1[0]) + Ui);
            o1.y = fexp2(fmaf(x1.y, kScale, v1[1]) + Ui);
            o1.z = fexp2(fmaf(x1.z, kScale, v1[2]) + Ui);
            o1.w = fexp2(fmaf(x1.w, kScale, v1[3]) + Ui);
            *reinterpret_cast<float4*>(Ob + (size_t)i * BN + c0) = o0;
            *reinterpret_cast<float4*>(Ob + (size_t)i * BN + c1) = o1;
        }
    }
}

extern "C" void kernel_launch(void* const* d_in, const int* in_sizes, int n_in,
                              void* d_out, int out_size, void* d_ws, size_t ws_size,
                              hipStream_t stream) {
    const float* logits = (const float*)d_in[0];
    float* out = (float*)d_out;
    const int B = in_sizes[0] / (BN * BN);   // 256
    hipLaunchKernelGGL(sinkhorn_fused, dim3(B), dim3(1024), 0, stream, logits, out);
}

// Round 2
// 393.150 us; speedup vs baseline: 1.2130x; 1.2130x over previous
//
#include <hip/hip_runtime.h>

#define BN 512            // matrix dimension n
#define NW 16             // waves per block (1024 threads)
#define RPW (BN / NW)     // rows per wave = 32

// Z = logits / TAU in base-2: t = logits * (log2(e)/tau)
static constexpr float kScale = 28.853900817779268f;
// int16 log-domain quantization of N = 2^(t + u1): q = rint(log2N * kQS), log2N in [-170, 0]
static constexpr float kQS  = 192.0f;
static constexpr float kQSi = 1.0f / 192.0f;

__device__ __forceinline__ float fexp2(float x) { return __builtin_amdgcn_exp2f(x); }
__device__ __forceinline__ float flog2(float x) { return __builtin_amdgcn_logf(x); }

__global__ __launch_bounds__(1024, 1) void sinkhorn_fused(
    const float* __restrict__ logits, float* __restrict__ out)
{
    __shared__ float U1[BN];         // u1 (log2 domain) from pass 0
    __shared__ float Bf[BN];         // linear col factor 2^v
    __shared__ float SL[BN];         // last row-sums (for final u)
    __shared__ float cred[NW][BN];   // per-wave column partials (32 KB)

    const int b = blockIdx.x;
    const size_t base = (size_t)b * BN * BN;
    const float* __restrict__ Zb = logits + base;
    float* __restrict__ Ob = out + base;
    short* __restrict__ Nq = (short*)Ob;   // 512 KB int16 scratch inside this batch's out slice

    const int tid  = threadIdx.x;
    const int lane = tid & 63;
    const int wave = tid >> 6;
    const int c0 = lane * 4;          // cols [c0..c0+3] and [c1..c1+3] owned by this lane
    const int c1 = lane * 4 + 256;

    // ---------------- pass 0: fp32 read, exact row LSE, quantize N ----------------
    {
        float ca0[4] = {0.f,0.f,0.f,0.f};
        float ca1[4] = {0.f,0.f,0.f,0.f};

        for (int r = 0; r < RPW; ++r) {
            const int i = wave * RPW + r;
            const float4 x0 = *reinterpret_cast<const float4*>(Zb + (size_t)i * BN + c0);
            const float4 x1 = *reinterpret_cast<const float4*>(Zb + (size_t)i * BN + c1);

            float t[8];
            t[0] = x0.x * kScale; t[1] = x0.y * kScale; t[2] = x0.z * kScale; t[3] = x0.w * kScale;
            t[4] = x1.x * kScale; t[5] = x1.y * kScale; t[6] = x1.z * kScale; t[7] = x1.w * kScale;

            // exact row max (raw Z/tau overflows 2^127 otherwise)
            float m = t[0];
            #pragma unroll
            for (int k = 1; k < 8; ++k) m = fmaxf(m, t[k]);
            #pragma unroll
            for (int d = 32; d > 0; d >>= 1) m = fmaxf(m, __shfl_xor(m, d, 64));

            float p[8], s = 0.f;
            #pragma unroll
            for (int k = 0; k < 8; ++k) { t[k] = t[k] - m; p[k] = fexp2(t[k]); s += p[k]; }
            #pragma unroll
            for (int d = 32; d > 0; d >>= 1) s += __shfl_xor(s, d, 64);

            const float lg2s = flog2(s);
            const float w = __builtin_amdgcn_rcpf(s);
            if (lane == 0) U1[i] = -m - lg2s;          // u1_i

            // column accumulation of N = p*w  (rows of N sum to 1)
            #pragma unroll
            for (int k = 0; k < 4; ++k) ca0[k] = fmaf(p[k],     w, ca0[k]);
            #pragma unroll
            for (int k = 0; k < 4; ++k) ca1[k] = fmaf(p[4 + k], w, ca1[k]);

            // quantize log2(N) = (t-m) - lg2s to int16; clamp at -170 (contributions provably dead)
            int q[8];
            #pragma unroll
            for (int k = 0; k < 8; ++k) {
                float v = fmaxf(t[k] - lg2s, -170.0f);
                q[k] = (int)rintf(v * kQS);
            }
            int4 packed;
            packed.x = (q[0] & 0xffff) | (q[1] << 16);
            packed.y = (q[2] & 0xffff) | (q[3] << 16);
            packed.z = (q[4] & 0xffff) | (q[5] << 16);
            packed.w = (q[6] & 0xffff) | (q[7] << 16);
            *reinterpret_cast<int4*>(Nq + (size_t)i * BN + lane * 8) = packed;
        }

        #pragma unroll
        for (int k = 0; k < 4; ++k) { cred[wave][c0 + k] = ca0[k]; cred[wave][c1 + k] = ca1[k]; }
        __syncthreads();
        if (tid < BN) {
            float s = 0.f;
            #pragma unroll
            for (int wv = 0; wv < NW; ++wv) s += cred[wv][tid];
            Bf[tid] = __builtin_amdgcn_rcpf(s);        // 2^{v1}
        }
        __syncthreads();
    }

    // ---------------- passes 1..9: linear Sinkhorn on int16-log N (L3-resident) ----------------
    for (int it = 1; it < 10; ++it) {
        float bl[8];
        #pragma unroll
        for (int k = 0; k < 4; ++k) { bl[k] = Bf[c0 + k]; bl[4 + k] = Bf[c1 + k]; }

        float ca0[4] = {0.f,0.f,0.f,0.f};
        float ca1[4] = {0.f,0.f,0.f,0.f};

        for (int r = 0; r < RPW; ++r) {
            const int i = wave * RPW + r;
            const int4 raw = *reinterpret_cast<const int4*>(Nq + (size_t)i * BN + lane * 8);

            float e[8];
            e[0] = fexp2((float)((raw.x << 16) >> 16) * kQSi);
            e[1] = fexp2((float)( raw.x        >> 16) * kQSi);
            e[2] = fexp2((float)((raw.y << 16) >> 16) * kQSi);
            e[3] = fexp2((float)( raw.y        >> 16) * kQSi);
            e[4] = fexp2((float)((raw.z << 16) >> 16) * kQSi);
            e[5] = fexp2((float)( raw.z        >> 16) * kQSi);
            e[6] = fexp2((float)((raw.w << 16) >> 16) * kQSi);
            e[7] = fexp2((float)( raw.w        >> 16) * kQSi);

            float sa = 0.f, sb = 0.f;
            #pragma unroll
            for (int k = 0; k < 4; ++k) { sa = fmaf(e[k], bl[k], sa); sb = fmaf(e[4+k], bl[4+k], sb); }
            float s = sa + sb;
            #pragma unroll
            for (int d = 32; d > 0; d >>= 1) s += __shfl_xor(s, d, 64);

            const float A = __builtin_amdgcn_rcpf(s);  // 2^{u - u1}
            if (lane == 0) SL[i] = s;

            #pragma unroll
            for (int k = 0; k < 4; ++k) ca0[k] = fmaf(e[k],     A, ca0[k]);
            #pragma unroll
            for (int k = 0; k < 4; ++k) ca1[k] = fmaf(e[4 + k], A, ca1[k]);
        }

        #pragma unroll
        for (int k = 0; k < 4; ++k) { cred[wave][c0 + k] = ca0[k]; cred[wave][c1 + k] = ca1[k]; }
        __syncthreads();
        if (tid < BN) {
            float s = 0.f;
            #pragma unroll
            for (int wv = 0; wv < NW; ++wv) s += cred[wv][tid];
            Bf[tid] = __builtin_amdgcn_rcpf(s);
        }
        __syncthreads();
    }

    // ---------------- finalize potentials, output pass from fp32 Z ----------------
    if (tid < BN) {
        U1[tid] = U1[tid] - flog2(SL[tid]);   // u_final
        Bf[tid] = flog2(Bf[tid]);             // v_final (log2)
    }
    __syncthreads();

    {
        float v0[4], v1[4];
        #pragma unroll
        for (int k = 0; k < 4; ++k) { v0[k] = Bf[c0 + k]; v1[k] = Bf[c1 + k]; }

        for (int r = 0; r < RPW; ++r) {
            const int i = wave * RPW + r;
            const float Ui = U1[i];
            const float4 x0 = *reinterpret_cast<const float4*>(Zb + (size_t)i * BN + c0);
            const float4 x1 = *reinterpret_cast<const float4*>(Zb + (size_t)i * BN + c1);
            float4 o0, o1;
            o0.x = fexp2(fmaf(x0.x, kScale, v0[0]) + Ui);
            o0.y = fexp2(fmaf(x0.y, kScale, v0[1]) + Ui);
            o0.z = fexp2(fmaf(x0.z, kScale, v0[2]) + Ui);
            o0.w = fexp2(fmaf(x0.w, kScale, v0[3]) + Ui);
            o1.x = fexp2(fmaf(x1.x, kScale, v1[0]) + Ui);
            o1.y = fexp2(fmaf(x1.y, kScale, v1[1]) + Ui);
            o1.z = fexp2(fmaf(x1.z, kScale, v1[2]) + Ui);
            o1.w = fexp2(fmaf(x1.w, kScale, v1[3]) + Ui);
            *reinterpret_cast<float4*>(Ob + (size_t)i * BN + c0) = o0;
            *reinterpret_cast<float4*>(Ob + (size_t)i * BN + c1) = o1;
        }
    }
}

extern "C" void kernel_launch(void* const* d_in, const int* in_sizes, int n_in,
                              void* d_out, int out_size, void* d_ws, size_t ws_size,
                              hipStream_t stream) {
    const float* logits = (const float*)d_in[0];
    float* out = (float*)d_out;
    const int B = in_sizes[0] / (BN * BN);   // 256
    hipLaunchKernelGGL(sinkhorn_fused, dim3(B), dim3(1024), 0, stream, logits, out);
}

// Round 3
// 345.890 us; speedup vs baseline: 1.3788x; 1.1366x over previous
//
#include <hip/hip_runtime.h>

#define BN 512            // matrix dimension n
#define NW 16             // waves per block (1024 threads)
#define RPW (BN / NW)     // rows per wave = 32

// t = logits * (log2(e)/tau)
static constexpr float kScale = 28.853900817779268f;

__device__ __forceinline__ float fexp2(float x){ return __builtin_amdgcn_exp2f(x); }
__device__ __forceinline__ float flog2(float x){ return __builtin_amdgcn_logf(x); }
__device__ __forceinline__ float frcp (float x){ return __builtin_amdgcn_rcpf(x); }

// round-to-nearest-even f32->bf16, pack two into a u32 (a=lo16, b=hi16)
__device__ __forceinline__ unsigned rtne_pack(float a, float b){
    unsigned ua = __float_as_uint(a), ub = __float_as_uint(b);
    unsigned lo = (ua + 0x7fffu + ((ua >> 16) & 1u)) >> 16;
    unsigned hi = (ub + 0x7fffu + ((ub >> 16) & 1u)) & 0xffff0000u;
    return lo | hi;
}
__device__ __forceinline__ void unpack2(unsigned w, float& lo, float& hi){
    lo = __uint_as_float(w << 16);
    hi = __uint_as_float(w & 0xffff0000u);
}

__global__ __launch_bounds__(1024, 1) void sinkhorn_fused(
    const float* __restrict__ logits, float* __restrict__ out,
    unsigned short* __restrict__ ws, int use_ws)
{
    __shared__ float Bf[BN];         // linear col factor (B)
    __shared__ float SL[BN];         // pass-9 row sums (-> final A)
    __shared__ float cred[NW][BN];   // per-wave column partials (32 KB)

    const int b = blockIdx.x;
    const size_t base = (size_t)b * BN * BN;
    const float* __restrict__ Zb = logits + base;
    float* __restrict__ Ob = out + base;
    // M: bf16, scaled 2^64, PERMUTED col layout (lane's 8 cols {4l..4l+3, 256+4l..+3} stored at [8l..8l+8))
    unsigned short* __restrict__ Mb = use_ws ? (ws + base) : (unsigned short*)Ob;

    const int tid  = threadIdx.x;
    const int lane = tid & 63;
    const int wave = tid >> 6;

    // ---------------- pass 0: fp32 read, exact row LSE, M = 2^(t-m-lg2s+64) in bf16 ----------------
    {
        float ca[8] = {0.f,0.f,0.f,0.f,0.f,0.f,0.f,0.f};

        for (int r = 0; r < RPW; ++r) {
            const int i = wave * RPW + r;
            const float4 x0 = *reinterpret_cast<const float4*>(Zb + (size_t)i * BN + 4 * lane);
            const float4 x1 = *reinterpret_cast<const float4*>(Zb + (size_t)i * BN + 256 + 4 * lane);

            float t[8];
            t[0] = x0.x * kScale; t[1] = x0.y * kScale; t[2] = x0.z * kScale; t[3] = x0.w * kScale;
            t[4] = x1.x * kScale; t[5] = x1.y * kScale; t[6] = x1.z * kScale; t[7] = x1.w * kScale;

            float m = t[0];
            #pragma unroll
            for (int k = 1; k < 8; ++k) m = fmaxf(m, t[k]);
            #pragma unroll
            for (int d = 32; d > 0; d >>= 1) m = fmaxf(m, __shfl_xor(m, d, 64));

            float p[8], s = 0.f;
            #pragma unroll
            for (int k = 0; k < 8; ++k) { p[k] = fexp2(t[k] - m); s += p[k]; }
            #pragma unroll
            for (int d = 32; d > 0; d >>= 1) s += __shfl_xor(s, d, 64);

            const float f = fexp2(64.0f - flog2(s));   // 2^64 / s
            float Mv[8];
            #pragma unroll
            for (int k = 0; k < 8; ++k) { Mv[k] = p[k] * f; ca[k] += Mv[k]; }

            int4 packed;
            packed.x = (int)rtne_pack(Mv[0], Mv[1]);
            packed.y = (int)rtne_pack(Mv[2], Mv[3]);
            packed.z = (int)rtne_pack(Mv[4], Mv[5]);
            packed.w = (int)rtne_pack(Mv[6], Mv[7]);
            *reinterpret_cast<int4*>(Mb + (size_t)i * BN + lane * 8) = packed;
        }

        #pragma unroll
        for (int k = 0; k < 8; ++k) cred[wave][8 * lane + k] = ca[k];
        __syncthreads();
        if (tid < BN) {
            float s = 0.f;
            #pragma unroll
            for (int wv = 0; wv < NW; ++wv) s += cred[wv][tid];
            Bf[tid] = frcp(s);            // B_1 (M-scale)
        }
        __syncthreads();
    }

    // ---------------- passes 1..9: pure-linear Sinkhorn on bf16 M ----------------
    const int g  = lane >> 5;            // row subgroup (2 rows in flight per wave)
    const int gl = lane & 31;

    for (int it = 1; it < 10; ++it) {
        float bl0[8], bl1[8];
        #pragma unroll
        for (int k = 0; k < 8; ++k) { bl0[k] = Bf[gl * 8 + k]; bl1[k] = Bf[256 + gl * 8 + k]; }

        float ca0[8] = {0.f,0.f,0.f,0.f,0.f,0.f,0.f,0.f};
        float ca1[8] = {0.f,0.f,0.f,0.f,0.f,0.f,0.f,0.f};

        #pragma unroll 4
        for (int step = 0; step < RPW / 2; ++step) {
            const int i = wave * RPW + 2 * step + g;
            const int4 w0 = *reinterpret_cast<const int4*>(Mb + (size_t)i * BN + gl * 8);
            const int4 w1 = *reinterpret_cast<const int4*>(Mb + (size_t)i * BN + 256 + gl * 8);

            float e0[8], e1[8];
            unpack2((unsigned)w0.x, e0[0], e0[1]); unpack2((unsigned)w0.y, e0[2], e0[3]);
            unpack2((unsigned)w0.z, e0[4], e0[5]); unpack2((unsigned)w0.w, e0[6], e0[7]);
            unpack2((unsigned)w1.x, e1[0], e1[1]); unpack2((unsigned)w1.y, e1[2], e1[3]);
            unpack2((unsigned)w1.z, e1[4], e1[5]); unpack2((unsigned)w1.w, e1[6], e1[7]);

            float sa = 0.f, sb = 0.f;
            #pragma unroll
            for (int k = 0; k < 8; ++k) { sa = fmaf(e0[k], bl0[k], sa); sb = fmaf(e1[k], bl1[k], sb); }
            float s = sa + sb;
            #pragma unroll
            for (int d = 16; d > 0; d >>= 1) s += __shfl_xor(s, d, 64);   // 32-lane group reduce

            const float A = frcp(s);
            if (it == 9 && gl == 0) SL[i] = s;

            #pragma unroll
            for (int k = 0; k < 8; ++k) { ca0[k] = fmaf(e0[k], A, ca0[k]); ca1[k] = fmaf(e1[k], A, ca1[k]); }
        }

        // combine the two row-subgroups, write per-wave col partials
        #pragma unroll
        for (int k = 0; k < 8; ++k) {
            ca0[k] += __shfl_xor(ca0[k], 32, 64);
            ca1[k] += __shfl_xor(ca1[k], 32, 64);
        }
        if (lane < 32) {
            #pragma unroll
            for (int k = 0; k < 8; ++k) {
                cred[wave][gl * 8 + k]       = ca0[k];
                cred[wave][256 + gl * 8 + k] = ca1[k];
            }
        }
        __syncthreads();
        if (tid < BN) {
            float s = 0.f;
            #pragma unroll
            for (int wv = 0; wv < NW; ++wv) s += cred[wv][tid];
            Bf[tid] = frcp(s);
        }
        __syncthreads();
    }

    // ---------------- final: out = M * A_i * B_j (reads M, writes fp32 over it) ----------------
    {
        float bf[8];
        #pragma unroll
        for (int k = 0; k < 8; ++k) bf[k] = Bf[8 * lane + k];

        auto emit_row = [&](int j) {
            const int4 w = *reinterpret_cast<const int4*>(Mb + (size_t)j * BN + lane * 8);
            float e[8];
            unpack2((unsigned)w.x, e[0], e[1]); unpack2((unsigned)w.y, e[2], e[3]);
            unpack2((unsigned)w.z, e[4], e[5]); unpack2((unsigned)w.w, e[6], e[7]);
            const float A = frcp(SL[j]);
            float4 o0, o1;
            o0.x = e[0] * A * bf[0]; o0.y = e[1] * A * bf[1];
            o0.z = e[2] * A * bf[2]; o0.w = e[3] * A * bf[3];
            o1.x = e[4] * A * bf[4]; o1.y = e[5] * A * bf[5];
            o1.z = e[6] * A * bf[6]; o1.w = e[7] * A * bf[7];
            *reinterpret_cast<float4*>(Ob + (size_t)j * BN + 4 * lane) = o0;
            *reinterpret_cast<float4*>(Ob + (size_t)j * BN + 256 + 4 * lane) = o1;
        };

        // descending power-of-2 ranges: fp32 write of row j clobbers M rows 2j,2j+1,
        // which always lie in an already-consumed (higher) range.
        for (int L = 256; L >= 1; L >>= 1) {
            for (int j = L + wave; j < 2 * L; j += NW) emit_row(j);
            __syncthreads();
        }
        if (wave == 0) emit_row(0);
    }
}

extern "C" void kernel_launch(void* const* d_in, const int* in_sizes, int n_in,
                              void* d_out, int out_size, void* d_ws, size_t ws_size,
                              hipStream_t stream) {
    const float* logits = (const float*)d_in[0];
    float* out = (float*)d_out;
    const int B = in_sizes[0] / (BN * BN);   // 256
    const size_t need = (size_t)B * BN * BN * sizeof(unsigned short);  // 128 MB
    const int use_ws = (ws_size >= need) ? 1 : 0;
    hipLaunchKernelGGL(sinkhorn_fused, dim3(B), dim3(1024), 0, stream,
                       logits, out, (unsigned short*)d_ws, use_ws);
}